// Round 2
// baseline (1184.636 us; speedup 1.0000x reference)
//
#include <hip/hip_runtime.h>

#define NB 32
#define NP 1024
#define KNB 20
#define INFF __builtin_inff()

// ---------------------------------------------------------------------------
// transpose X [NB*NP, C] -> Xt [NB][C][NP] and squared norms sq [NB*NP]
// ---------------------------------------------------------------------------
template<int C>
__global__ __launch_bounds__(256) void transpose_sq_kernel(const float* __restrict__ X,
                                                           float* __restrict__ Xt,
                                                           float* __restrict__ sq) {
    int p = blockIdx.x * 256 + threadIdx.x;   // grid sized exactly to NB*NP
    int g = p >> 10;
    int lp = p & 1023;
    const float* xr = X + (size_t)p * C;
    float s = 0.f;
#pragma unroll
    for (int c = 0; c < C; c++) {
        float v = xr[c];
        s = fmaf(v, v, s);
        Xt[((size_t)g * C + c) * NP + lp] = v;   // coalesced per c
    }
    sq[p] = s;
}

// ---------------------------------------------------------------------------
// KNN: one wave per 4 consecutive rows (same graph; 1024 % 4 == 0).
// Lane owns j = t*256 + lane*4 + e  (t,e in 0..3)  -> 16 candidates/lane/row,
// loaded as float4 and SHARED across the 4 rows (4x less L2 traffic, 16x
// fewer load instrs than row-per-wave scalar).
// Top-20 per row via iterative min-extraction; the 4 rows' shuffle
// butterflies interleave inside each round for ILP.
// Tie-break: lower j (matches jax.lax.top_k stable selection).
// idx out: global row index (g*NP + j), [NB*NP, KNB]
// ---------------------------------------------------------------------------
template<int C>
__global__ __launch_bounds__(256) void knn_kernel(const float* __restrict__ Xt,
                                                  const float* __restrict__ sq,
                                                  int* __restrict__ idx) {
    const int lane = threadIdx.x & 63;
    const int wave = threadIdx.x >> 6;
    const int row0 = blockIdx.x * 16 + wave * 4;   // 4 rows per wave
    const int g  = row0 >> 10;
    const int i0 = row0 & 1023;
    const float* __restrict__ Xg  = Xt + (size_t)g * C * NP;
    const float* __restrict__ sqg = sq + g * NP;

    // d[r][t*4+e] starts as dot(x_{i0+r}, x_j), becomes distance
    float d[4][16];
#pragma unroll
    for (int r = 0; r < 4; r++)
#pragma unroll
        for (int q = 0; q < 16; q++) d[r][q] = 0.f;

#pragma unroll 4
    for (int c = 0; c < C; c++) {
        const float4* col = (const float4*)(Xg + (size_t)c * NP);
        float4 xj[4];
#pragma unroll
        for (int t = 0; t < 4; t++) xj[t] = col[t * 64 + lane];   // coalesced 16B
#pragma unroll
        for (int r = 0; r < 4; r++) {
            float xic = Xg[(size_t)c * NP + i0 + r];               // L1 broadcast
#pragma unroll
            for (int t = 0; t < 4; t++) {
                d[r][t*4+0] = fmaf(xj[t].x, xic, d[r][t*4+0]);
                d[r][t*4+1] = fmaf(xj[t].y, xic, d[r][t*4+1]);
                d[r][t*4+2] = fmaf(xj[t].z, xic, d[r][t*4+2]);
                d[r][t*4+3] = fmaf(xj[t].w, xic, d[r][t*4+3]);
            }
        }
    }

    // finalize distances: d = sq_i + sq_j - 2*dot ; self -> inf
    float4 s4[4];
#pragma unroll
    for (int t = 0; t < 4; t++) s4[t] = ((const float4*)sqg)[t * 64 + lane];
#pragma unroll
    for (int r = 0; r < 4; r++) {
        float sqi = sqg[i0 + r];
#pragma unroll
        for (int t = 0; t < 4; t++) {
#pragma unroll
            for (int e = 0; e < 4; e++) {
                int j = t * 256 + lane * 4 + e;
                float sj = ((const float*)&s4[t])[e];
                float dist = sqi + sj - 2.f * d[r][t*4+e];
                d[r][t*4+e] = (j == i0 + r) ? INFF : dist;
            }
        }
    }

    int* out = idx + (size_t)row0 * KNB;
    const int gbase = g * NP;

#pragma unroll 1
    for (int rnd = 0; rnd < KNB; rnd++) {
#pragma unroll
        for (int r = 0; r < 4; r++) {
            // per-lane argmin over 16 (ascending-j iteration => lower-j ties win)
            float v = d[r][0];
            int ji = lane * 4;
#pragma unroll
            for (int q = 1; q < 16; q++) {
                int j = (q >> 2) * 256 + lane * 4 + (q & 3);
                bool lt = (d[r][q] < v);
                v  = lt ? d[r][q] : v;
                ji = lt ? j : ji;
            }
            // wave butterfly argmin, ties -> lower j
#pragma unroll
            for (int off = 32; off >= 1; off >>= 1) {
                float ov = __shfl_xor(v, off);
                int   oj = __shfl_xor(ji, off);
                if (ov < v || (ov == v && oj < ji)) { v = ov; ji = oj; }
            }
            if (lane == 0) out[r * KNB + rnd] = gbase + ji;
            // clear winner (compile-time indexing only)
            if (((ji >> 2) & 63) == lane) {
                int qq = ((ji >> 8) << 2) | (ji & 3);
#pragma unroll
                for (int q = 0; q < 16; q++)
                    if (q == qq) d[r][q] = INFF;
            }
        }
    }
}

// ---------------------------------------------------------------------------
// Edge-MLP decomposition:  feat@W = xi@(Wt-Wb) + xj@Wb, and since ReLU and
// per-channel max commute with the xi-constant part:
//   out_i = relu( A_i + max_j Bm_j ),  A = X@(Wt-Wb)+b,  Bm = X@Wb.
// W is [2*Cin, H] row-major (Wt = rows 0..Cin-1, Wb = rows Cin..2Cin-1).
// ---------------------------------------------------------------------------
template<int Cin, int H>
__global__ __launch_bounds__(256) void linear_kernel(const float* __restrict__ X,
                                                     const float* __restrict__ W,
                                                     const float* __restrict__ b,
                                                     float* __restrict__ A,
                                                     float* __restrict__ Bm) {
    int tid = blockIdx.x * 256 + threadIdx.x;   // i*H + h (grid exact)
    int i = tid / H;
    int h = tid % H;
    const float* xi = X + (size_t)i * Cin;
    float a = b[h];
    float bm = 0.f;
#pragma unroll 8
    for (int c = 0; c < Cin; c++) {
        float x  = xi[c];                       // wave-broadcast via L1
        float wt = W[c * H + h];                // coalesced
        float wb = W[(Cin + c) * H + h];
        a  = fmaf(x, wt - wb, a);
        bm = fmaf(x, wb, bm);
    }
    A[tid]  = a;
    Bm[tid] = bm;
}

// ---------------------------------------------------------------------------
// out_i[h] = relu(A_i[h] + max_{j in knn(i)} Bm_j[h]); float4 over h.
// out may alias A (thread reads A[tid], writes out[tid]).
// ---------------------------------------------------------------------------
template<int H>
__global__ __launch_bounds__(256) void gathermax_kernel(const float* __restrict__ A,
                                                        const float* __restrict__ Bm,
                                                        const int* __restrict__ idx,
                                                        float* __restrict__ out) {
    int tid = blockIdx.x * 256 + threadIdx.x;   // over NB*NP*(H/4)
    int i = tid / (H / 4);
    int q = tid % (H / 4);
    const int* ii = idx + (size_t)i * KNB;
    float4 m = make_float4(-INFF, -INFF, -INFF, -INFF);
#pragma unroll
    for (int r = 0; r < KNB; r++) {
        int j = ii[r];                          // shared across H/4 threads (L1)
        float4 v = ((const float4*)(Bm + (size_t)j * H))[q];
        m.x = fmaxf(m.x, v.x); m.y = fmaxf(m.y, v.y);
        m.z = fmaxf(m.z, v.z); m.w = fmaxf(m.w, v.w);
    }
    float4 a = ((const float4*)A)[tid];
    float4 o;
    o.x = fmaxf(a.x + m.x, 0.f); o.y = fmaxf(a.y + m.y, 0.f);
    o.z = fmaxf(a.z + m.z, 0.f); o.w = fmaxf(a.w + m.w, 0.f);
    ((float4*)out)[tid] = o;
}

// ---------------------------------------------------------------------------
// global max-pool over P then FC(128->128) + relu. One block per graph.
// ---------------------------------------------------------------------------
__global__ __launch_bounds__(128) void pool_fc_kernel(const float* __restrict__ h3,
                                                      const float* __restrict__ Wfc,
                                                      const float* __restrict__ bfc,
                                                      float* __restrict__ out) {
    int g = blockIdx.x;
    int c = threadIdx.x;                        // 0..127
    const float* hg = h3 + (size_t)g * NP * 128;
    float m = -INFF;
#pragma unroll 8
    for (int p = 0; p < NP; p++)
        m = fmaxf(m, hg[p * 128 + c]);          // coalesced across c
    __shared__ float pooled[128];
    pooled[c] = m;
    __syncthreads();
    float acc = bfc[c];
#pragma unroll 8
    for (int k = 0; k < 128; k++)
        acc = fmaf(pooled[k], Wfc[k * 128 + c], acc);
    out[g * 128 + c] = fmaxf(acc, 0.f);
}

// ---------------------------------------------------------------------------
// Workspace layout (bytes):
//   sq  : [NB*NP]           f32   131072
//   idx : [NB*NP*KNB]       i32   2621440
//   P1  : [NB*NP*128]       f32   16 MB   (A/h for layers 1,3; final h3)
//   P2  : [NB*NP*128]       f32   16 MB   (A/h for layer 2)
//   BB  : [NB*NP*128]       f32   16 MB   (Bm each layer; Xt aliases its head
//                                          — Xt is dead before Bm is written)
// total ~50.6 MB
// ---------------------------------------------------------------------------
extern "C" void kernel_launch(void* const* d_in, const int* in_sizes, int n_in,
                              void* d_out, int out_size, void* d_ws, size_t ws_size,
                              hipStream_t stream) {
    const float* x   = (const float*)d_in[0];
    // d_in[1] = batch (unused: graphs are equal-sized, reshape semantics)
    const float* W1  = (const float*)d_in[2];
    const float* b1  = (const float*)d_in[3];
    const float* W2  = (const float*)d_in[4];
    const float* b2  = (const float*)d_in[5];
    const float* W3  = (const float*)d_in[6];
    const float* b3  = (const float*)d_in[7];
    const float* Wfc = (const float*)d_in[8];
    const float* bfc = (const float*)d_in[9];
    float* out = (float*)d_out;

    char* ws = (char*)d_ws;
    float* sqb  = (float*)(ws);
    int*   idxb = (int*)  (ws + 131072);
    float* P1   = (float*)(ws + 2752512);
    float* P2   = (float*)(ws + 19529728);
    float* BB   = (float*)(ws + 36306944);
    float* Xt   = BB;   // alias: Xt fully consumed by knn before Bm is written

    const int rowsBlocks = NB * NP / 256;            // 128
    const int knnBlocks  = NB * NP / 16;             // 2048 (16 rows/block)
    const int lin64      = NB * NP * 64 / 256;       // 8192
    const int lin128     = NB * NP * 128 / 256;      // 16384
    const int gm64       = NB * NP * (64/4) / 256;   // 2048
    const int gm128      = NB * NP * (128/4) / 256;  // 4096

    // ---- layer 1 (C=3 -> H=64) ----
    transpose_sq_kernel<3><<<rowsBlocks, 256, 0, stream>>>(x, Xt, sqb);
    knn_kernel<3><<<knnBlocks, 256, 0, stream>>>(Xt, sqb, idxb);
    linear_kernel<3, 64><<<lin64, 256, 0, stream>>>(x, W1, b1, P1, BB);
    gathermax_kernel<64><<<gm64, 256, 0, stream>>>(P1, BB, idxb, P1);

    // ---- layer 2 (C=64 -> H=64) ----
    transpose_sq_kernel<64><<<rowsBlocks, 256, 0, stream>>>(P1, Xt, sqb);
    knn_kernel<64><<<knnBlocks, 256, 0, stream>>>(Xt, sqb, idxb);
    linear_kernel<64, 64><<<lin64, 256, 0, stream>>>(P1, W2, b2, P2, BB);
    gathermax_kernel<64><<<gm64, 256, 0, stream>>>(P2, BB, idxb, P2);

    // ---- layer 3 (C=64 -> H=128) ----
    transpose_sq_kernel<64><<<rowsBlocks, 256, 0, stream>>>(P2, Xt, sqb);
    knn_kernel<64><<<knnBlocks, 256, 0, stream>>>(Xt, sqb, idxb);
    linear_kernel<64, 128><<<lin128, 256, 0, stream>>>(P2, W3, b3, P1, BB);
    gathermax_kernel<128><<<gm128, 256, 0, stream>>>(P1, BB, idxb, P1);

    // ---- global max-pool + FC ----
    pool_fc_kernel<<<NB, 128, 0, stream>>>(P1, Wfc, bfc, out);
}

// Round 10
// 809.930 us; speedup vs baseline: 1.4626x; 1.4626x over previous
//
#include <hip/hip_runtime.h>

#define NB 32
#define NP 1024
#define KNB 20
#define INFF __builtin_inff()

// ---------------------------------------------------------------------------
// wave64 butterfly reductions via __shfl_xor (proven-safe on this harness in
// round 2). Result is uniform across all lanes. ~6 ops each; used only
// ~15-35 times per wave, so latency is negligible.
// ---------------------------------------------------------------------------
__device__ __forceinline__ unsigned wred_add(unsigned v) {
#pragma unroll
    for (int off = 32; off >= 1; off >>= 1) v += (unsigned)__shfl_xor((int)v, off);
    return v;
}
__device__ __forceinline__ unsigned wred_and(unsigned v) {
#pragma unroll
    for (int off = 32; off >= 1; off >>= 1) v &= (unsigned)__shfl_xor((int)v, off);
    return v;
}
__device__ __forceinline__ unsigned wred_or(unsigned v) {
#pragma unroll
    for (int off = 32; off >= 1; off >>= 1) v |= (unsigned)__shfl_xor((int)v, off);
    return v;
}

// ---------------------------------------------------------------------------
// transpose X [NB*NP, C] -> Xt [NB][C][NP] and squared norms sq [NB*NP]
// ---------------------------------------------------------------------------
template<int C>
__global__ __launch_bounds__(256) void transpose_sq_kernel(const float* __restrict__ X,
                                                           float* __restrict__ Xt,
                                                           float* __restrict__ sq) {
    int p = blockIdx.x * 256 + threadIdx.x;
    int g = p >> 10;
    int lp = p & 1023;
    const float* xr = X + (size_t)p * C;
    float s = 0.f;
#pragma unroll
    for (int c = 0; c < C; c++) {
        float v = xr[c];
        s = fmaf(v, v, s);
        Xt[((size_t)g * C + c) * NP + lp] = v;
    }
    sq[p] = s;
}

// ---------------------------------------------------------------------------
// KNN: binary-search radix select on monotone u32 keys.
// One wave = 4 consecutive rows. Lane owns j = t*256 + lane*4 + e.
// Distance arithmetic bit-identical to round-2 (absmax was 0.0 — keep set).
//
//   - keys: monotone map of f32 distance (self -> UINT_MAX)
//   - per row: range [Wlo, Wlo+2^(bs+1)) from AND/OR of real keys
//   - round b: M = Wlo + 2^b; tot = #{key < M} (2 VALU/cand + reduce)
//       tot == 20 -> EXACT separation, done (early exit, typical ~10-14 rnds)
//       tot  < 20 -> Wlo = M
//   - emit: ballot+mbcnt compaction of {key < M}; rare tie path extracts
//     remaining equals by smallest j (matches jax.lax.top_k tie rule).
// Output order within a row is arbitrary — gathermax is order-invariant.
// ---------------------------------------------------------------------------
template<int C>
__global__ __launch_bounds__(256) void knn_kernel(const float* __restrict__ Xt,
                                                  const float* __restrict__ sq,
                                                  int* __restrict__ idx) {
    const int lane = threadIdx.x & 63;
    const int wave = threadIdx.x >> 6;
    const int row0 = blockIdx.x * 16 + wave * 4;
    const int g  = row0 >> 10;
    const int i0 = row0 & 1023;
    const float* __restrict__ Xg  = Xt + (size_t)g * C * NP;
    const float* __restrict__ sqg = sq + g * NP;
    const int j4 = lane * 4;

    // ---- phase 1: dot products (shared j-loads across 4 rows) ----
    float d[4][16];
#pragma unroll
    for (int r = 0; r < 4; r++)
#pragma unroll
        for (int q = 0; q < 16; q++) d[r][q] = 0.f;

#pragma unroll 4
    for (int c = 0; c < C; c++) {
        const float4* col = (const float4*)(Xg + (size_t)c * NP);
        float4 xj[4];
#pragma unroll
        for (int t = 0; t < 4; t++) xj[t] = col[t * 64 + lane];
#pragma unroll
        for (int r = 0; r < 4; r++) {
            float xic = Xg[(size_t)c * NP + i0 + r];
#pragma unroll
            for (int t = 0; t < 4; t++) {
                d[r][t*4+0] = fmaf(xj[t].x, xic, d[r][t*4+0]);
                d[r][t*4+1] = fmaf(xj[t].y, xic, d[r][t*4+1]);
                d[r][t*4+2] = fmaf(xj[t].z, xic, d[r][t*4+2]);
                d[r][t*4+3] = fmaf(xj[t].w, xic, d[r][t*4+3]);
            }
        }
    }

    // ---- phase 2: distances -> monotone u32 keys; gather AND/OR range ----
    float4 s4[4];
#pragma unroll
    for (int t = 0; t < 4; t++) s4[t] = ((const float4*)sqg)[t * 64 + lane];

    unsigned K[4][16];
    unsigned Wlo[4]; unsigned Mex[4]; int bs[4];
    int bmax = 0;
#pragma unroll
    for (int r = 0; r < 4; r++) {
        float sqi = sqg[i0 + r];
        unsigned av = 0xFFFFFFFFu, ov = 0u;
#pragma unroll
        for (int t = 0; t < 4; t++) {
#pragma unroll
            for (int e = 0; e < 4; e++) {
                int j = t * 256 + j4 + e;
                float sj = (e == 0) ? s4[t].x : (e == 1) ? s4[t].y : (e == 2) ? s4[t].z : s4[t].w;
                float dist = sqi + sj - 2.f * d[r][t*4+e];   // identical to r2
                unsigned u = __float_as_uint(dist);
                unsigned key = u ^ (((int)u < 0) ? 0xFFFFFFFFu : 0x80000000u);
                bool self = (j == i0 + r);
                K[r][t*4+e] = self ? 0xFFFFFFFFu : key;
                av &= self ? 0xFFFFFFFFu : key;   // AND over real keys
                ov |= self ? 0u : key;            // OR  over real keys (self excluded)
            }
        }
        av = wred_and(av);
        ov = wred_or(ov);
        unsigned x = av ^ ov;
        int b = 31 - __clz((int)x);               // -1 if all keys equal
        bs[r] = b;
        unsigned wmask = (b >= 31) ? 0xFFFFFFFFu : ((b < 0) ? 0u : ((2u << b) - 1u));
        Wlo[r] = av & ~wmask;                     // common prefix; no key < Wlo
        Mex[r] = 0;
        if (b > bmax) bmax = b;
    }

    // ---- phase 3: bit bisection with early exit ----
    int doneM = 0;
    for (int b = bmax; b >= 0 && doneM != 0xF; b--) {   // uniform bounds
#pragma unroll
        for (int r = 0; r < 4; r++) {
            if ((doneM & (1 << r)) || b > bs[r]) continue;  // uniform guards
            unsigned M = Wlo[r] + (1u << b);
            unsigned c = 0;
#pragma unroll
            for (int q = 0; q < 16; q++) c += (K[r][q] < M) ? 1u : 0u;
            unsigned tot = wred_add(c);
            if (tot == KNB)      { Mex[r] = M; doneM |= (1 << r); }
            else if (tot < KNB)  { Wlo[r] = M; }
        }
    }

    // ---- phase 4: emit ----
    const int gbase = g * NP;
#pragma unroll
    for (int r = 0; r < 4; r++) {
        int* outr = idx + (size_t)(row0 + r) * KNB;
        const bool tie = !(doneM & (1 << r));
        const unsigned M = tie ? Wlo[r] : Mex[r];   // tie: M = p (20th key value)
        unsigned bpos = 0;
#pragma unroll
        for (int t = 0; t < 4; t++) {
#pragma unroll
            for (int e = 0; e < 4; e++) {
                bool w = K[r][t*4+e] < M;           // strict less: unambiguous
                unsigned long long mm = __ballot(w);
                unsigned pos = bpos + __builtin_amdgcn_mbcnt_hi(
                                   (unsigned)(mm >> 32),
                                   __builtin_amdgcn_mbcnt_lo((unsigned)mm, 0u));
                if (w) outr[pos] = gbase + t * 256 + j4 + e;
                bpos += (unsigned)__popcll(mm);
            }
        }
        if (tie) {
            // need = 20 - bpos equals (== M), take smallest j (top_k tie rule)
            const unsigned p = M;
            const int nneed = KNB - (int)bpos;      // >= 1, wave-uniform
            for (int n = 0; n < nneed; n++) {       // rare path
                int jm = 0x7FFFFFFF;
#pragma unroll
                for (int t = 0; t < 4; t++)
#pragma unroll
                    for (int e = 0; e < 4; e++)
                        if (K[r][t*4+e] == p) jm = min(jm, t * 256 + j4 + e);
#pragma unroll
                for (int off = 32; off >= 1; off >>= 1)
                    jm = min(jm, __shfl_xor(jm, off));
                if (((jm >> 2) & 63) == lane) {     // owner lane stores+clears
                    outr[bpos + n] = gbase + jm;
                    int qq = ((jm >> 8) << 2) | (jm & 3);
#pragma unroll
                    for (int q = 0; q < 16; q++)
                        if (q == qq) K[r][q] = 0xFFFFFFFFu;
                }
            }
        }
    }
}

// ---------------------------------------------------------------------------
// Edge-MLP decomposition:  feat@W = xi@(Wt-Wb) + xj@Wb; ReLU & max commute:
//   out_i = relu( A_i + max_j Bm_j ),  A = X@(Wt-Wb)+b,  Bm = X@Wb.
// ---------------------------------------------------------------------------
template<int Cin, int H>
__global__ __launch_bounds__(256) void linear_kernel(const float* __restrict__ X,
                                                     const float* __restrict__ W,
                                                     const float* __restrict__ b,
                                                     float* __restrict__ A,
                                                     float* __restrict__ Bm) {
    int tid = blockIdx.x * 256 + threadIdx.x;
    int i = tid / H;
    int h = tid % H;
    const float* xi = X + (size_t)i * Cin;
    float a = b[h];
    float bm = 0.f;
#pragma unroll 8
    for (int c = 0; c < Cin; c++) {
        float x  = xi[c];
        float wt = W[c * H + h];
        float wb = W[(Cin + c) * H + h];
        a  = fmaf(x, wt - wb, a);
        bm = fmaf(x, wb, bm);
    }
    A[tid]  = a;
    Bm[tid] = bm;
}

// ---------------------------------------------------------------------------
// out_i[h] = relu(A_i[h] + max_{j in knn(i)} Bm_j[h]); float4 over h.
// ---------------------------------------------------------------------------
template<int H>
__global__ __launch_bounds__(256) void gathermax_kernel(const float* __restrict__ A,
                                                        const float* __restrict__ Bm,
                                                        const int* __restrict__ idx,
                                                        float* __restrict__ out) {
    int tid = blockIdx.x * 256 + threadIdx.x;
    int i = tid / (H / 4);
    int q = tid % (H / 4);
    const int* ii = idx + (size_t)i * KNB;
    float4 m = make_float4(-INFF, -INFF, -INFF, -INFF);
#pragma unroll
    for (int r = 0; r < KNB; r++) {
        int j = ii[r];
        float4 v = ((const float4*)(Bm + (size_t)j * H))[q];
        m.x = fmaxf(m.x, v.x); m.y = fmaxf(m.y, v.y);
        m.z = fmaxf(m.z, v.z); m.w = fmaxf(m.w, v.w);
    }
    float4 a = ((const float4*)A)[tid];
    float4 o;
    o.x = fmaxf(a.x + m.x, 0.f); o.y = fmaxf(a.y + m.y, 0.f);
    o.z = fmaxf(a.z + m.z, 0.f); o.w = fmaxf(a.w + m.w, 0.f);
    ((float4*)out)[tid] = o;
}

// ---------------------------------------------------------------------------
// global max-pool over P then FC(128->128) + relu. One block per graph.
// ---------------------------------------------------------------------------
__global__ __launch_bounds__(128) void pool_fc_kernel(const float* __restrict__ h3,
                                                      const float* __restrict__ Wfc,
                                                      const float* __restrict__ bfc,
                                                      float* __restrict__ out) {
    int g = blockIdx.x;
    int c = threadIdx.x;
    const float* hg = h3 + (size_t)g * NP * 128;
    float m = -INFF;
#pragma unroll 8
    for (int p = 0; p < NP; p++)
        m = fmaxf(m, hg[p * 128 + c]);
    __shared__ float pooled[128];
    pooled[c] = m;
    __syncthreads();
    float acc = bfc[c];
#pragma unroll 8
    for (int k = 0; k < 128; k++)
        acc = fmaf(pooled[k], Wfc[k * 128 + c], acc);
    out[g * 128 + c] = fmaxf(acc, 0.f);
}

// ---------------------------------------------------------------------------
// Workspace layout identical to round 2 (~50.6 MB).
// ---------------------------------------------------------------------------
extern "C" void kernel_launch(void* const* d_in, const int* in_sizes, int n_in,
                              void* d_out, int out_size, void* d_ws, size_t ws_size,
                              hipStream_t stream) {
    const float* x   = (const float*)d_in[0];
    const float* W1  = (const float*)d_in[2];
    const float* b1  = (const float*)d_in[3];
    const float* W2  = (const float*)d_in[4];
    const float* b2  = (const float*)d_in[5];
    const float* W3  = (const float*)d_in[6];
    const float* b3  = (const float*)d_in[7];
    const float* Wfc = (const float*)d_in[8];
    const float* bfc = (const float*)d_in[9];
    float* out = (float*)d_out;

    char* ws = (char*)d_ws;
    float* sqb  = (float*)(ws);
    int*   idxb = (int*)  (ws + 131072);
    float* P1   = (float*)(ws + 2752512);
    float* P2   = (float*)(ws + 19529728);
    float* BB   = (float*)(ws + 36306944);
    float* Xt   = BB;   // alias: Xt fully consumed by knn before Bm is written

    const int rowsBlocks = NB * NP / 256;            // 128
    const int knnBlocks  = NB * NP / 16;             // 2048
    const int lin64      = NB * NP * 64 / 256;       // 8192
    const int lin128     = NB * NP * 128 / 256;      // 16384
    const int gm64       = NB * NP * (64/4) / 256;   // 2048
    const int gm128      = NB * NP * (128/4) / 256;  // 4096

    // ---- layer 1 (C=3 -> H=64) ----
    transpose_sq_kernel<3><<<rowsBlocks, 256, 0, stream>>>(x, Xt, sqb);
    knn_kernel<3><<<knnBlocks, 256, 0, stream>>>(Xt, sqb, idxb);
    linear_kernel<3, 64><<<lin64, 256, 0, stream>>>(x, W1, b1, P1, BB);
    gathermax_kernel<64><<<gm64, 256, 0, stream>>>(P1, BB, idxb, P1);

    // ---- layer 2 (C=64 -> H=64) ----
    transpose_sq_kernel<64><<<rowsBlocks, 256, 0, stream>>>(P1, Xt, sqb);
    knn_kernel<64><<<knnBlocks, 256, 0, stream>>>(Xt, sqb, idxb);
    linear_kernel<64, 64><<<lin64, 256, 0, stream>>>(P1, W2, b2, P2, BB);
    gathermax_kernel<64><<<gm64, 256, 0, stream>>>(P2, BB, idxb, P2);

    // ---- layer 3 (C=64 -> H=128) ----
    transpose_sq_kernel<64><<<rowsBlocks, 256, 0, stream>>>(P2, Xt, sqb);
    knn_kernel<64><<<knnBlocks, 256, 0, stream>>>(Xt, sqb, idxb);
    linear_kernel<64, 128><<<lin128, 256, 0, stream>>>(P2, W3, b3, P1, BB);
    gathermax_kernel<128><<<gm128, 256, 0, stream>>>(P1, BB, idxb, P1);

    // ---- global max-pool + FC ----
    pool_fc_kernel<<<NB, 128, 0, stream>>>(P1, Wfc, bfc, out);
}